// Round 4
// baseline (179.456 us; speedup 1.0000x reference)
//
#include <hip/hip_runtime.h>
#include <hip/hip_bf16.h>

#define S_LEN 4096
#define HID   768
#define NH    12
#define HD    64

typedef __attribute__((ext_vector_type(8))) __bf16 bf16x8;
typedef __attribute__((ext_vector_type(4))) float  f32x4;

// round-to-nearest-even fp32 -> bf16
__device__ __forceinline__ unsigned short f2bf(float f) {
  union { float f; unsigned u; } v; v.f = f;
  unsigned r = v.u + 0x7fffu + ((v.u >> 16) & 1u);
  return (unsigned short)(r >> 16);
}

// truncating pack of two fp32 into [bf16(hi) | bf16(lo)] — single v_perm_b32.
__device__ __forceinline__ unsigned pktr(float lo, float hi) {
  union { float f; unsigned u; } a, b; a.f = lo; b.f = hi;
  return __builtin_amdgcn_perm(b.u, a.u, 0x07060302u);
}

// async global->LDS DMA, 16B/lane. LDS dest = wave-uniform base + lane*16.
#define GLL(gp, lp) __builtin_amdgcn_global_load_lds(                      \
    (__attribute__((address_space(1))) void*)(gp),                         \
    (__attribute__((address_space(3))) void*)(lp), 16, 0, 0)

// ---------------------------------------------------------------------------
// Prep: X->bf16 | W->Wt bf16 transposed.
// ---------------------------------------------------------------------------
__global__ __launch_bounds__(256) void prep(
    const float* __restrict__ X,
    const float* __restrict__ Wq, const float* __restrict__ Wk, const float* __restrict__ Wv,
    unsigned short* __restrict__ Xb, unsigned short* __restrict__ Wt)
{
  const int b = blockIdx.x, tid = threadIdx.x;
  __shared__ unsigned short T[64][72];

  if (b < 3072) {                      // X fp32 -> bf16
    const int i = b * 256 + tid;
    const float4 v = ((const float4*)X)[i];
    ushort4 o;
    o.x = f2bf(v.x); o.y = f2bf(v.y); o.z = f2bf(v.z); o.w = f2bf(v.w);
    ((ushort4*)Xb)[i] = o;
  } else {                             // W [k][n] -> Wt [n][k] bf16, 64x64 tiles
    const int t = b - 3072;
    const int z = t / 144, rem = t % 144;
    const int k0 = (rem / 12) * 64, n0 = (rem % 12) * 64;
    const float* W = (z == 0) ? Wq : (z == 1) ? Wk : Wv;
    unsigned short* Od = Wt + (size_t)z * HID * HID;
    #pragma unroll
    for (int i = tid; i < 512; i += 256) {
      const int kr = i >> 3, c8 = (i & 7) * 8;
      const float4 a = *(const float4*)&W[(size_t)(k0 + kr) * HID + n0 + c8];
      const float4 bb = *(const float4*)&W[(size_t)(k0 + kr) * HID + n0 + c8 + 4];
      T[kr][c8 + 0] = f2bf(a.x);  T[kr][c8 + 1] = f2bf(a.y);
      T[kr][c8 + 2] = f2bf(a.z);  T[kr][c8 + 3] = f2bf(a.w);
      T[kr][c8 + 4] = f2bf(bb.x); T[kr][c8 + 5] = f2bf(bb.y);
      T[kr][c8 + 6] = f2bf(bb.z); T[kr][c8 + 7] = f2bf(bb.w);
    }
    __syncthreads();
    #pragma unroll
    for (int i = tid; i < 512; i += 256) {
      const int nr = i >> 3, c8 = (i & 7) * 8;
      ushort4 lo, hi;
      lo.x = T[c8 + 0][nr]; lo.y = T[c8 + 1][nr]; lo.z = T[c8 + 2][nr]; lo.w = T[c8 + 3][nr];
      hi.x = T[c8 + 4][nr]; hi.y = T[c8 + 5][nr]; hi.z = T[c8 + 6][nr]; hi.w = T[c8 + 7][nr];
      ushort4* dst = (ushort4*)&Od[(size_t)(n0 + nr) * HID + k0 + c8];
      dst[0] = lo; dst[1] = hi;
    }
  }
}

// ---------------------------------------------------------------------------
// Kernel 1: QKV projection, 128x64 WG tile. 4 waves x 32 rows each -> per
// wave-slab 12 LDS reads : 16 MFMA (was 10:8). Grid (12 h, 32 mt, 3 z).
// Single-buffered 24 KB LDS, GLL staging with pre-swizzled source
// (invariant LDS[r][x] = G[r][x ^ ((r&7)*8)]).
// Q pre-scaled by 0.125*log2(e). V written [h][d][s_p], perm for 32-row
// waves: s_p = wave*32 + g*8 + r + mt*4.
// launch_bounds (256,2): 128-VGPR cap — (256,4)'s 64-VGPR cap would spill
// (~70+ live VGPRs in the K-loop).
// ---------------------------------------------------------------------------
__global__ __launch_bounds__(256, 2) void qkv_proj(
    const unsigned short* __restrict__ Xb, const unsigned short* __restrict__ Wt,
    const float* __restrict__ bq, const float* __restrict__ bk, const float* __restrict__ bv,
    unsigned short* __restrict__ Qo, unsigned short* __restrict__ Ko, unsigned short* __restrict__ Vo)
{
  const int z = blockIdx.z;
  const unsigned short* W = Wt + (size_t)z * HID * HID;   // [n][k]
  const float* bias = (z == 0) ? bq : (z == 1) ? bk : bv;
  unsigned short* Out = (z == 0) ? Qo : (z == 1) ? Ko : Vo;

  const int tid  = threadIdx.x;
  const int wave = tid >> 6;
  const int lane = tid & 63;
  const int g = lane >> 4, c = lane & 15;
  const int h  = blockIdx.x;
  const int n0 = h * 64;
  const int m0 = blockIdx.y * 128;

  __shared__ unsigned short Xl[8192];   // [128][64] swizzled
  __shared__ unsigned short Wl[4096];   // [64][64]  swizzled

  // staging: pre-swizzled source column (involution within 8-row groups)
  const int sr  = lane >> 3;
  const int scb = ((lane & 7) ^ sr) * 8;
  const unsigned short* xG = &Xb[(size_t)(m0 + wave * 32 + sr) * HID + scb];
  const unsigned short* wG = &W[(size_t)(n0 + wave * 16 + sr) * HID + scb];

  const int swz = (c & 7) * 8;
  unsigned aRi[2][2], bRi[4][2];
  #pragma unroll
  for (int mt = 0; mt < 2; ++mt)
    #pragma unroll
    for (int kk = 0; kk < 2; ++kk)
      aRi[mt][kk] = (wave * 32 + mt * 16 + c) * 64 + ((kk * 32 + g * 8) ^ swz);
  #pragma unroll
  for (int nt = 0; nt < 4; ++nt)
    #pragma unroll
    for (int kk = 0; kk < 2; ++kk)
      bRi[nt][kk] = (nt * 16 + c) * 64 + ((kk * 32 + g * 8) ^ swz);

  f32x4 acc[2][4];
  #pragma unroll
  for (int mt = 0; mt < 2; ++mt)
    #pragma unroll
    for (int nt = 0; nt < 4; ++nt) acc[mt][nt] = (f32x4){0.f, 0.f, 0.f, 0.f};

  // prologue: stage slab 0
  #pragma unroll
  for (int i = 0; i < 4; ++i) GLL(xG + (size_t)i * 8 * HID, &Xl[(wave * 4 + i) * 512]);
  #pragma unroll
  for (int j = 0; j < 2; ++j) GLL(wG + (size_t)j * 8 * HID, &Wl[(wave * 2 + j) * 512]);
  xG += 64; wG += 64;

  for (int k0 = 0; k0 < HID; k0 += 64) {
    __syncthreads();                 // drains GLL -> slab ready

    const bf16x8 a00 = *(const bf16x8*)&Xl[aRi[0][0]];
    const bf16x8 a01 = *(const bf16x8*)&Xl[aRi[0][1]];
    const bf16x8 a10 = *(const bf16x8*)&Xl[aRi[1][0]];
    const bf16x8 a11 = *(const bf16x8*)&Xl[aRi[1][1]];
    #pragma unroll
    for (int nt = 0; nt < 4; ++nt) {
      const bf16x8 b0 = *(const bf16x8*)&Wl[bRi[nt][0]];
      const bf16x8 b1 = *(const bf16x8*)&Wl[bRi[nt][1]];
      acc[0][nt] = __builtin_amdgcn_mfma_f32_16x16x32_bf16(a00, b0, acc[0][nt], 0, 0, 0);
      acc[0][nt] = __builtin_amdgcn_mfma_f32_16x16x32_bf16(a01, b1, acc[0][nt], 0, 0, 0);
      acc[1][nt] = __builtin_amdgcn_mfma_f32_16x16x32_bf16(a10, b0, acc[1][nt], 0, 0, 0);
      acc[1][nt] = __builtin_amdgcn_mfma_f32_16x16x32_bf16(a11, b1, acc[1][nt], 0, 0, 0);
    }

    __syncthreads();                 // all reads of this slab done
    if (k0 + 64 < HID) {
      #pragma unroll
      for (int i = 0; i < 4; ++i) GLL(xG + (size_t)i * 8 * HID, &Xl[(wave * 4 + i) * 512]);
      #pragma unroll
      for (int j = 0; j < 2; ++j) GLL(wG + (size_t)j * 8 * HID, &Wl[(wave * 2 + j) * 512]);
      xG += 64; wG += 64;
    }
  }

  // epilogue: restage through Xl (swizzled) -> coalesced b128 stores
  const float qsc = (z == 0) ? 0.1803368782f : 1.0f;   // 0.125 * log2(e)
  #pragma unroll
  for (int mt = 0; mt < 2; ++mt) {
    #pragma unroll
    for (int nt = 0; nt < 4; ++nt) {
      const float bv_ = bias[n0 + nt * 16 + c];
      #pragma unroll
      for (int r = 0; r < 4; ++r) {
        const unsigned short val = f2bf((acc[mt][nt][r] + bv_) * qsc);
        if (z == 2) {
          // V: Xl as [64][128]: row=d, col = s_p = wave*32 + g*8 + r + mt*4
          const int d = nt * 16 + c;
          const int col = wave * 32 + g * 8 + r + mt * 4;
          Xl[d * 128 + (col ^ ((d & 7) * 8))] = val;
        } else {
          const int row = wave * 32 + mt * 16 + 4 * g + r;
          const int col = nt * 16 + c;
          Xl[row * 64 + (col ^ ((row & 7) * 8))] = val;
        }
      }
    }
  }
  __syncthreads();
  #pragma unroll
  for (int jj = 0; jj < 4; ++jj) {
    const int j = tid + 256 * jj;
    if (z == 2) {
      const int d = j >> 4, c8 = (j & 15) * 8;
      const bf16x8 v = *(const bf16x8*)&Xl[d * 128 + (c8 ^ ((d & 7) * 8))];
      *(bf16x8*)&Out[((size_t)h * HD + d) * S_LEN + m0 + c8] = v;     // [h][d][s_p]
    } else {
      const int row = j >> 3, c8 = (j & 7) * 8;
      const bf16x8 v = *(const bf16x8*)&Xl[row * 64 + (c8 ^ ((row & 7) * 8))];
      *(bf16x8*)&Out[((size_t)h * S_LEN + m0 + row) * HD + c8] = v;   // [h][s][d]
    }
  }
}

// ---------------------------------------------------------------------------
// Kernel 2: attention, templated on KV-split NSP. 2 waves x 64 q = 128 q/WG.
// NSP=4: 1536 WGs -> LDS-capped 5 WGs/CU -> ~10 waves/CU (fixes R2's 13%
// occupancy while keeping the halved LDS-read economics).
// XCD-pinned 1-D grid: each XCD owns NH*NSP/8 (h,sp) pairs -> K/V L2-resident.
// Double-buffered K/V LDS, ONE barrier/iter, GLL staging, plain-store partials.
// ---------------------------------------------------------------------------
template<int NSP>
__global__ __launch_bounds__(128, 2) void attn(
    const unsigned short* __restrict__ Q, const unsigned short* __restrict__ K,
    const unsigned short* __restrict__ Vp,   // [h][d][s_p]
    float* __restrict__ O, float* __restrict__ Opb, float* __restrict__ Lp)
{
  const int b   = blockIdx.x;          // 0 .. 32*NH*NSP-1
  const int xcd = b & 7;
  const int idx = b >> 3;
  const int pg  = idx >> 5;            // 0 .. NH*NSP/8 - 1
  const int qt  = idx & 31;
  const int pair = xcd + 8 * pg;       // 0 .. NH*NSP-1, pinned per XCD
  const int h  = pair / NSP;
  const int sp = pair % NSP;

  const int tid  = threadIdx.x;
  const int wave = tid >> 6;           // 0..1
  const int lane = tid & 63;
  const int g = lane >> 4, c = lane & 15;
  const int q0 = qt * 128;
  const int k_base = sp * (S_LEN / NSP);
  const int NIT = (S_LEN / NSP) / 64;

  __shared__ unsigned short KB[2][4096];   // [key][d] swizzled
  __shared__ unsigned short VB[2][4096];   // [d][key_p] swizzled

  // Q B-frags (loop-invariant): each wave owns 64 q rows = 4 s-tiles
  bf16x8 aq[4][2];
  #pragma unroll
  for (int s = 0; s < 4; ++s) {
    const size_t qrow = (size_t)h * S_LEN + q0 + wave * 64 + s * 16 + c;
    aq[s][0] = *(const bf16x8*)&Q[qrow * HD + g * 8];
    aq[s][1] = *(const bf16x8*)&Q[qrow * HD + 32 + g * 8];
  }

  bf16x8 bones8;   // B column 0 = 1.0 -> C[:,0] = row sums
  {
    const unsigned short one_bf = (c == 0) ? 0x3F80u : 0u;
    #pragma unroll
    for (int j = 0; j < 8; ++j) ((unsigned short*)&bones8)[j] = one_bf;
  }

  const int swz = (c & 7) * 8;
  unsigned kRi[8];             // read offsets; identical pattern serves K and V
  #pragma unroll
  for (int mt = 0; mt < 4; ++mt) {
    kRi[2 * mt]     = (mt * 16 + c) * 64 + ((g * 8) ^ swz);
    kRi[2 * mt + 1] = (mt * 16 + c) * 64 + ((32 + g * 8) ^ swz);
  }

  const int sr  = lane >> 3;
  const int scb = ((lane & 7) ^ sr) * 8;
  const unsigned short* kG = &K[((size_t)h * S_LEN + k_base + wave * 32 + sr) * HD + scb];
  const unsigned short* vG = &Vp[((size_t)h * HD + wave * 32 + sr) * S_LEN + k_base + scb];

  // prologue: slab 0 into buffer 0
  #pragma unroll
  for (int i = 0; i < 4; ++i) {
    GLL(kG + (size_t)i * 8 * HD,    &KB[0][(wave * 4 + i) * 512]);
    GLL(vG + (size_t)i * 8 * S_LEN, &VB[0][(wave * 4 + i) * 512]);
  }
  kG += (size_t)64 * HD; vG += 64;

  f32x4 o[4][4];
  #pragma unroll
  for (int s = 0; s < 4; ++s)
    #pragma unroll
    for (int dt = 0; dt < 4; ++dt) o[s][dt] = (f32x4){0.f, 0.f, 0.f, 0.f};
  f32x4 lacc[4] = {{0.f,0.f,0.f,0.f},{0.f,0.f,0.f,0.f},{0.f,0.f,0.f,0.f},{0.f,0.f,0.f,0.f}};

  for (int kt = 0; kt < NIT; ++kt) {
    __syncthreads();                 // drains DMA into buf[cur]; frees buf[cur^1]
    const int cur = kt & 1;
    if (kt + 1 < NIT) {              // async-prefetch next slab into other buffer
      const int nxt = cur ^ 1;
      #pragma unroll
      for (int i = 0; i < 4; ++i) {
        GLL(kG + (size_t)i * 8 * HD,    &KB[nxt][(wave * 4 + i) * 512]);
        GLL(vG + (size_t)i * 8 * S_LEN, &VB[nxt][(wave * 4 + i) * 512]);
      }
      kG += (size_t)64 * HD; vG += 64;
    }
    const unsigned short* Kl = KB[cur];
    const unsigned short* Vt = VB[cur];

    // S^T = K Q^T per 16-key tile; exp2 + pack; concat pairs -> x32 A-frags
    bf16x8 apack[4][2];
    #pragma unroll
    for (int t = 0; t < 2; ++t) {
      const bf16x8 kf00 = *(const bf16x8*)&Kl[kRi[4 * t + 0]];
      const bf16x8 kf01 = *(const bf16x8*)&Kl[kRi[4 * t + 1]];
      const bf16x8 kf10 = *(const bf16x8*)&Kl[kRi[4 * t + 2]];
      const bf16x8 kf11 = *(const bf16x8*)&Kl[kRi[4 * t + 3]];
      #pragma unroll
      for (int s = 0; s < 4; ++s) {
        f32x4 sa = {0.f,0.f,0.f,0.f}, sb = {0.f,0.f,0.f,0.f};
        sa = __builtin_amdgcn_mfma_f32_16x16x32_bf16(kf00, aq[s][0], sa, 0, 0, 0);
        sa = __builtin_amdgcn_mfma_f32_16x16x32_bf16(kf01, aq[s][1], sa, 0, 0, 0);
        sb = __builtin_amdgcn_mfma_f32_16x16x32_bf16(kf10, aq[s][0], sb, 0, 0, 0);
        sb = __builtin_amdgcn_mfma_f32_16x16x32_bf16(kf11, aq[s][1], sb, 0, 0, 0);
        union { unsigned u[4]; bf16x8 v; } pk;
        pk.u[0] = pktr(__builtin_amdgcn_exp2f(sa[0]), __builtin_amdgcn_exp2f(sa[1]));
        pk.u[1] = pktr(__builtin_amdgcn_exp2f(sa[2]), __builtin_amdgcn_exp2f(sa[3]));
        pk.u[2] = pktr(__builtin_amdgcn_exp2f(sb[0]), __builtin_amdgcn_exp2f(sb[1]));
        pk.u[3] = pktr(__builtin_amdgcn_exp2f(sb[2]), __builtin_amdgcn_exp2f(sb[3]));
        apack[s][t] = pk.v;
      }
    }

    __builtin_amdgcn_s_setprio(1);   // favor the pure-MFMA cluster (T5)
    #pragma unroll
    for (int dt = 0; dt < 4; ++dt) {
      const bf16x8 vb0 = *(const bf16x8*)&Vt[kRi[2 * dt]];
      const bf16x8 vb1 = *(const bf16x8*)&Vt[kRi[2 * dt + 1]];
      #pragma unroll
      for (int s = 0; s < 4; ++s) {
        o[s][dt] = __builtin_amdgcn_mfma_f32_16x16x32_bf16(apack[s][0], vb0, o[s][dt], 0, 0, 0);
        o[s][dt] = __builtin_amdgcn_mfma_f32_16x16x32_bf16(apack[s][1], vb1, o[s][dt], 0, 0, 0);
      }
    }
    #pragma unroll
    for (int s = 0; s < 4; ++s) {
      lacc[s] = __builtin_amdgcn_mfma_f32_16x16x32_bf16(apack[s][0], bones8, lacc[s], 0, 0, 0);
      lacc[s] = __builtin_amdgcn_mfma_f32_16x16x32_bf16(apack[s][1], bones8, lacc[s], 0, 0, 0);
    }
    __builtin_amdgcn_s_setprio(0);
  }

  // epilogue: plain stores of partials (each element written exactly once)
  float* __restrict__ Od = (sp == 0) ? O : Opb + (size_t)(sp - 1) * S_LEN * HID;
  #pragma unroll
  for (int s = 0; s < 4; ++s) {
    #pragma unroll
    for (int dt = 0; dt < 4; ++dt) {
      #pragma unroll
      for (int r = 0; r < 4; ++r) {
        const int row = q0 + wave * 64 + s * 16 + 4 * g + r;
        Od[(size_t)row * HID + h * HD + dt * 16 + c] = o[s][dt][r];
      }
    }
  }
  if (c == 0) {
    #pragma unroll
    for (int s = 0; s < 4; ++s)
      #pragma unroll
      for (int r = 0; r < 4; ++r) {
        const int row = q0 + wave * 64 + s * 16 + 4 * g + r;
        Lp[((size_t)sp * NH + h) * S_LEN + row] = lacc[s][r];
      }
  }
}

// ---------------------------------------------------------------------------
// Kernel 3: merge the NSP KV-split partials and normalize by the softmax
// denominator. Pure-BW.
// ---------------------------------------------------------------------------
template<int NSP>
__global__ __launch_bounds__(256) void reduce_norm(float* __restrict__ O,
                                                   const float* __restrict__ Opb,
                                                   const float* __restrict__ Lp)
{
  const int i = blockIdx.x * 256 + threadIdx.x;
  float4 a = ((const float4*)O)[i];
  const int idx4 = i * 4;
  const int row = idx4 / HID;
  const int h   = (idx4 % HID) >> 6;
  float l = Lp[h * S_LEN + row];
  #pragma unroll
  for (int s = 1; s < NSP; ++s) {
    const float4 b = ((const float4*)(Opb + (size_t)(s - 1) * S_LEN * HID))[i];
    a.x += b.x; a.y += b.y; a.z += b.z; a.w += b.w;
    l += Lp[((size_t)s * NH + h) * S_LEN + row];
  }
  const float inv = 1.0f / l;
  a.x *= inv; a.y *= inv; a.z *= inv; a.w *= inv;
  ((float4*)O)[i] = a;
}

// ---------------------------------------------------------------------------
extern "C" void kernel_launch(void* const* d_in, const int* in_sizes, int n_in,
                              void* d_out, int out_size, void* d_ws, size_t ws_size,
                              hipStream_t stream) {
  const float* X  = (const float*)d_in[0];
  const float* Wq = (const float*)d_in[1];
  const float* bq = (const float*)d_in[2];
  const float* Wk = (const float*)d_in[3];
  const float* bk = (const float*)d_in[4];
  const float* Wv = (const float*)d_in[5];
  const float* bv = (const float*)d_in[6];

  unsigned short* Xb = (unsigned short*)d_ws;
  unsigned short* Wt = Xb + (size_t)S_LEN * HID;
  unsigned short* Qb = Wt + (size_t)3 * HID * HID;
  unsigned short* Kb = Qb + (size_t)NH * S_LEN * HD;
  unsigned short* Vb = Kb + (size_t)NH * S_LEN * HD;
  float* Opb = (float*)(Vb + (size_t)NH * S_LEN * HD);

  // bytes needed for NSP=4: bf16 bufs + 3 O-partials + 4*NH*S L-partials
  const size_t ush = (size_t)S_LEN * HID + (size_t)3 * HID * HID + (size_t)3 * NH * S_LEN * HD;
  const size_t need4 = ush * 2 + ((size_t)3 * S_LEN * HID + (size_t)4 * NH * S_LEN) * 4;
  const bool s4 = ws_size >= need4;

  float* Lp = Opb + (size_t)(s4 ? 3 : 1) * S_LEN * HID;
  float* O = (float*)d_out;

  prep<<<dim3(3504), 256, 0, stream>>>(X, Wq, Wk, Wv, Xb, Wt);
  qkv_proj<<<dim3(12, 32, 3), 256, 0, stream>>>(Xb, Wt, bq, bk, bv, Qb, Kb, Vb);
  if (s4) {
    attn<4><<<dim3(1536), 128, 0, stream>>>(Qb, Kb, Vb, O, Opb, Lp);
    reduce_norm<4><<<dim3((S_LEN * HID / 4) / 256), 256, 0, stream>>>(O, Opb, Lp);
  } else {
    attn<2><<<dim3(768), 128, 0, stream>>>(Qb, Kb, Vb, O, Opb, Lp);
    reduce_norm<2><<<dim3((S_LEN * HID / 4) / 256), 256, 0, stream>>>(O, Opb, Lp);
  }
}

// Round 5
// 168.368 us; speedup vs baseline: 1.0659x; 1.0659x over previous
//
#include <hip/hip_runtime.h>
#include <hip/hip_bf16.h>

#define S_LEN 4096
#define HID   768
#define NH    12
#define HD    64

typedef __attribute__((ext_vector_type(8))) __bf16 bf16x8;
typedef __attribute__((ext_vector_type(4))) float  f32x4;

// round-to-nearest-even fp32 -> bf16
__device__ __forceinline__ unsigned short f2bf(float f) {
  union { float f; unsigned u; } v; v.f = f;
  unsigned r = v.u + 0x7fffu + ((v.u >> 16) & 1u);
  return (unsigned short)(r >> 16);
}

// truncating pack of two fp32 into [bf16(hi) | bf16(lo)] — single v_perm_b32.
__device__ __forceinline__ unsigned pktr(float lo, float hi) {
  union { float f; unsigned u; } a, b; a.f = lo; b.f = hi;
  return __builtin_amdgcn_perm(b.u, a.u, 0x07060302u);
}

// async global->LDS DMA, 16B/lane. LDS dest = wave-uniform base + lane*16.
#define GLL(gp, lp) __builtin_amdgcn_global_load_lds(                      \
    (__attribute__((address_space(1))) void*)(gp),                         \
    (__attribute__((address_space(3))) void*)(lp), 16, 0, 0)

// ---------------------------------------------------------------------------
// Prep: X->bf16 | W->Wt bf16 transposed.
// ---------------------------------------------------------------------------
__global__ __launch_bounds__(256) void prep(
    const float* __restrict__ X,
    const float* __restrict__ Wq, const float* __restrict__ Wk, const float* __restrict__ Wv,
    unsigned short* __restrict__ Xb, unsigned short* __restrict__ Wt)
{
  const int b = blockIdx.x, tid = threadIdx.x;
  __shared__ unsigned short T[64][72];

  if (b < 3072) {                      // X fp32 -> bf16
    const int i = b * 256 + tid;
    const float4 v = ((const float4*)X)[i];
    ushort4 o;
    o.x = f2bf(v.x); o.y = f2bf(v.y); o.z = f2bf(v.z); o.w = f2bf(v.w);
    ((ushort4*)Xb)[i] = o;
  } else {                             // W [k][n] -> Wt [n][k] bf16, 64x64 tiles
    const int t = b - 3072;
    const int z = t / 144, rem = t % 144;
    const int k0 = (rem / 12) * 64, n0 = (rem % 12) * 64;
    const float* W = (z == 0) ? Wq : (z == 1) ? Wk : Wv;
    unsigned short* Od = Wt + (size_t)z * HID * HID;
    #pragma unroll
    for (int i = tid; i < 512; i += 256) {
      const int kr = i >> 3, c8 = (i & 7) * 8;
      const float4 a = *(const float4*)&W[(size_t)(k0 + kr) * HID + n0 + c8];
      const float4 bb = *(const float4*)&W[(size_t)(k0 + kr) * HID + n0 + c8 + 4];
      T[kr][c8 + 0] = f2bf(a.x);  T[kr][c8 + 1] = f2bf(a.y);
      T[kr][c8 + 2] = f2bf(a.z);  T[kr][c8 + 3] = f2bf(a.w);
      T[kr][c8 + 4] = f2bf(bb.x); T[kr][c8 + 5] = f2bf(bb.y);
      T[kr][c8 + 6] = f2bf(bb.z); T[kr][c8 + 7] = f2bf(bb.w);
    }
    __syncthreads();
    #pragma unroll
    for (int i = tid; i < 512; i += 256) {
      const int nr = i >> 3, c8 = (i & 7) * 8;
      ushort4 lo, hi;
      lo.x = T[c8 + 0][nr]; lo.y = T[c8 + 1][nr]; lo.z = T[c8 + 2][nr]; lo.w = T[c8 + 3][nr];
      hi.x = T[c8 + 4][nr]; hi.y = T[c8 + 5][nr]; hi.z = T[c8 + 6][nr]; hi.w = T[c8 + 7][nr];
      ushort4* dst = (ushort4*)&Od[(size_t)(n0 + nr) * HID + k0 + c8];
      dst[0] = lo; dst[1] = hi;
    }
  }
}

// ---------------------------------------------------------------------------
// Kernel 1: QKV projection, 128x64 WG tile (unchanged from R4 — neutral but
// structurally better). GLL staging, pre-swizzled source, 24 KB LDS.
// Q pre-scaled by 0.125*log2(e). V written [h][d][s_p].
// ---------------------------------------------------------------------------
__global__ __launch_bounds__(256, 2) void qkv_proj(
    const unsigned short* __restrict__ Xb, const unsigned short* __restrict__ Wt,
    const float* __restrict__ bq, const float* __restrict__ bk, const float* __restrict__ bv,
    unsigned short* __restrict__ Qo, unsigned short* __restrict__ Ko, unsigned short* __restrict__ Vo)
{
  const int z = blockIdx.z;
  const unsigned short* W = Wt + (size_t)z * HID * HID;   // [n][k]
  const float* bias = (z == 0) ? bq : (z == 1) ? bk : bv;
  unsigned short* Out = (z == 0) ? Qo : (z == 1) ? Ko : Vo;

  const int tid  = threadIdx.x;
  const int wave = tid >> 6;
  const int lane = tid & 63;
  const int g = lane >> 4, c = lane & 15;
  const int h  = blockIdx.x;
  const int n0 = h * 64;
  const int m0 = blockIdx.y * 128;

  __shared__ unsigned short Xl[8192];   // [128][64] swizzled
  __shared__ unsigned short Wl[4096];   // [64][64]  swizzled

  const int sr  = lane >> 3;
  const int scb = ((lane & 7) ^ sr) * 8;
  const unsigned short* xG = &Xb[(size_t)(m0 + wave * 32 + sr) * HID + scb];
  const unsigned short* wG = &W[(size_t)(n0 + wave * 16 + sr) * HID + scb];

  const int swz = (c & 7) * 8;
  unsigned aRi[2][2], bRi[4][2];
  #pragma unroll
  for (int mt = 0; mt < 2; ++mt)
    #pragma unroll
    for (int kk = 0; kk < 2; ++kk)
      aRi[mt][kk] = (wave * 32 + mt * 16 + c) * 64 + ((kk * 32 + g * 8) ^ swz);
  #pragma unroll
  for (int nt = 0; nt < 4; ++nt)
    #pragma unroll
    for (int kk = 0; kk < 2; ++kk)
      bRi[nt][kk] = (nt * 16 + c) * 64 + ((kk * 32 + g * 8) ^ swz);

  f32x4 acc[2][4];
  #pragma unroll
  for (int mt = 0; mt < 2; ++mt)
    #pragma unroll
    for (int nt = 0; nt < 4; ++nt) acc[mt][nt] = (f32x4){0.f, 0.f, 0.f, 0.f};

  #pragma unroll
  for (int i = 0; i < 4; ++i) GLL(xG + (size_t)i * 8 * HID, &Xl[(wave * 4 + i) * 512]);
  #pragma unroll
  for (int j = 0; j < 2; ++j) GLL(wG + (size_t)j * 8 * HID, &Wl[(wave * 2 + j) * 512]);
  xG += 64; wG += 64;

  for (int k0 = 0; k0 < HID; k0 += 64) {
    __syncthreads();                 // drains GLL -> slab ready

    const bf16x8 a00 = *(const bf16x8*)&Xl[aRi[0][0]];
    const bf16x8 a01 = *(const bf16x8*)&Xl[aRi[0][1]];
    const bf16x8 a10 = *(const bf16x8*)&Xl[aRi[1][0]];
    const bf16x8 a11 = *(const bf16x8*)&Xl[aRi[1][1]];
    #pragma unroll
    for (int nt = 0; nt < 4; ++nt) {
      const bf16x8 b0 = *(const bf16x8*)&Wl[bRi[nt][0]];
      const bf16x8 b1 = *(const bf16x8*)&Wl[bRi[nt][1]];
      acc[0][nt] = __builtin_amdgcn_mfma_f32_16x16x32_bf16(a00, b0, acc[0][nt], 0, 0, 0);
      acc[0][nt] = __builtin_amdgcn_mfma_f32_16x16x32_bf16(a01, b1, acc[0][nt], 0, 0, 0);
      acc[1][nt] = __builtin_amdgcn_mfma_f32_16x16x32_bf16(a10, b0, acc[1][nt], 0, 0, 0);
      acc[1][nt] = __builtin_amdgcn_mfma_f32_16x16x32_bf16(a11, b1, acc[1][nt], 0, 0, 0);
    }

    __syncthreads();                 // all reads of this slab done
    if (k0 + 64 < HID) {
      #pragma unroll
      for (int i = 0; i < 4; ++i) GLL(xG + (size_t)i * 8 * HID, &Xl[(wave * 4 + i) * 512]);
      #pragma unroll
      for (int j = 0; j < 2; ++j) GLL(wG + (size_t)j * 8 * HID, &Wl[(wave * 2 + j) * 512]);
      xG += 64; wG += 64;
    }
  }

  // epilogue: restage through Xl (swizzled) -> coalesced b128 stores
  const float qsc = (z == 0) ? 0.1803368782f : 1.0f;   // 0.125 * log2(e)
  #pragma unroll
  for (int mt = 0; mt < 2; ++mt) {
    #pragma unroll
    for (int nt = 0; nt < 4; ++nt) {
      const float bv_ = bias[n0 + nt * 16 + c];
      #pragma unroll
      for (int r = 0; r < 4; ++r) {
        const unsigned short val = f2bf((acc[mt][nt][r] + bv_) * qsc);
        if (z == 2) {
          // V: Xl as [64][128]: row=d, col = s_p = wave*32 + g*8 + r + mt*4
          const int d = nt * 16 + c;
          const int col = wave * 32 + g * 8 + r + mt * 4;
          Xl[d * 128 + (col ^ ((d & 7) * 8))] = val;
        } else {
          const int row = wave * 32 + mt * 16 + 4 * g + r;
          const int col = nt * 16 + c;
          Xl[row * 64 + (col ^ ((row & 7) * 8))] = val;
        }
      }
    }
  }
  __syncthreads();
  #pragma unroll
  for (int jj = 0; jj < 4; ++jj) {
    const int j = tid + 256 * jj;
    if (z == 2) {
      const int d = j >> 4, c8 = (j & 15) * 8;
      const bf16x8 v = *(const bf16x8*)&Xl[d * 128 + (c8 ^ ((d & 7) * 8))];
      *(bf16x8*)&Out[((size_t)h * HD + d) * S_LEN + m0 + c8] = v;     // [h][d][s_p]
    } else {
      const int row = j >> 3, c8 = (j & 7) * 8;
      const bf16x8 v = *(const bf16x8*)&Xl[row * 64 + (c8 ^ ((row & 7) * 8))];
      *(bf16x8*)&Out[((size_t)h * S_LEN + m0 + row) * HD + c8] = v;   // [h][s][d]
    }
  }
}

// ---------------------------------------------------------------------------
// Kernel 2: attention — 4 waves x 64 q = 256 q/WG. Untested matrix cell:
// R1 (4w x 32q) = 59 us @ 8 waves/CU; R2/R4 (2w x 64q) = 71-74 us @ 4.5
// waves/CU (LDS caps residency at ~2 WGs/CU regardless of grid size — R4's
// grid doubling moved occupancy 13.4->14.1%, nothing). 4w x 64q keeps R1's
// 8 waves/CU residency AND R4's halved LDS-reads-per-MFMA (16 b128 : 72 MFMA).
// NSP=4 -> 768 WGs of 256 thr, NIT=16, 32 KB LDS, XCD-pinned (h,sp),
// double-buffered GLL staging, plain-store partials.
// ---------------------------------------------------------------------------
template<int NSP>
__global__ __launch_bounds__(256, 2) void attn(
    const unsigned short* __restrict__ Q, const unsigned short* __restrict__ K,
    const unsigned short* __restrict__ Vp,   // [h][d][s_p]
    float* __restrict__ O, float* __restrict__ Opb, float* __restrict__ Lp)
{
  const int b   = blockIdx.x;          // 0 .. 16*NH*NSP-1
  const int xcd = b & 7;
  const int idx = b >> 3;
  const int pg  = idx >> 4;            // 0 .. NH*NSP/8 - 1
  const int qt  = idx & 15;            // 0..15 (256-q tiles)
  const int pair = xcd + 8 * pg;       // pinned per XCD
  const int h  = pair / NSP;
  const int sp = pair % NSP;

  const int tid  = threadIdx.x;
  const int wave = tid >> 6;           // 0..3
  const int lane = tid & 63;
  const int g = lane >> 4, c = lane & 15;
  const int q0 = qt * 256;
  const int k_base = sp * (S_LEN / NSP);
  const int NIT = (S_LEN / NSP) / 64;

  __shared__ unsigned short KB[2][4096];   // [key][d] swizzled
  __shared__ unsigned short VB[2][4096];   // [d][key_p] swizzled

  // Q B-frags (loop-invariant): each wave owns 64 q rows = 4 s-tiles
  bf16x8 aq[4][2];
  #pragma unroll
  for (int s = 0; s < 4; ++s) {
    const size_t qrow = (size_t)h * S_LEN + q0 + wave * 64 + s * 16 + c;
    aq[s][0] = *(const bf16x8*)&Q[qrow * HD + g * 8];
    aq[s][1] = *(const bf16x8*)&Q[qrow * HD + 32 + g * 8];
  }

  bf16x8 bones8;   // B column 0 = 1.0 -> C[:,0] = row sums
  {
    const unsigned short one_bf = (c == 0) ? 0x3F80u : 0u;
    #pragma unroll
    for (int j = 0; j < 8; ++j) ((unsigned short*)&bones8)[j] = one_bf;
  }

  const int swz = (c & 7) * 8;
  unsigned kRi[8];             // read offsets; identical pattern serves K and V
  #pragma unroll
  for (int mt = 0; mt < 4; ++mt) {
    kRi[2 * mt]     = (mt * 16 + c) * 64 + ((g * 8) ^ swz);
    kRi[2 * mt + 1] = (mt * 16 + c) * 64 + ((32 + g * 8) ^ swz);
  }

  // staging: wave w, issue i in {0,1}: LDS bytes (w*2+i)*1024 + lane*16
  //   -> row (w*2+i)*8 + (lane>>3); source col pre-swizzled (involution)
  const int sr  = lane >> 3;
  const int scb = ((lane & 7) ^ sr) * 8;
  const unsigned short* kG = &K[((size_t)h * S_LEN + k_base + wave * 16 + sr) * HD + scb];
  const unsigned short* vG = &Vp[((size_t)h * HD + wave * 16 + sr) * S_LEN + k_base + scb];

  // prologue: slab 0 into buffer 0
  #pragma unroll
  for (int i = 0; i < 2; ++i) {
    GLL(kG + (size_t)i * 8 * HD,    &KB[0][(wave * 2 + i) * 512]);
    GLL(vG + (size_t)i * 8 * S_LEN, &VB[0][(wave * 2 + i) * 512]);
  }
  kG += (size_t)64 * HD; vG += 64;

  f32x4 o[4][4];
  #pragma unroll
  for (int s = 0; s < 4; ++s)
    #pragma unroll
    for (int dt = 0; dt < 4; ++dt) o[s][dt] = (f32x4){0.f, 0.f, 0.f, 0.f};
  f32x4 lacc[4] = {{0.f,0.f,0.f,0.f},{0.f,0.f,0.f,0.f},{0.f,0.f,0.f,0.f},{0.f,0.f,0.f,0.f}};

  for (int kt = 0; kt < NIT; ++kt) {
    __syncthreads();                 // drains DMA into buf[cur]; frees buf[cur^1]
    const int cur = kt & 1;
    if (kt + 1 < NIT) {              // async-prefetch next slab into other buffer
      const int nxt = cur ^ 1;
      #pragma unroll
      for (int i = 0; i < 2; ++i) {
        GLL(kG + (size_t)i * 8 * HD,    &KB[nxt][(wave * 2 + i) * 512]);
        GLL(vG + (size_t)i * 8 * S_LEN, &VB[nxt][(wave * 2 + i) * 512]);
      }
      kG += (size_t)64 * HD; vG += 64;
    }
    const unsigned short* Kl = KB[cur];
    const unsigned short* Vt = VB[cur];

    // S^T = K Q^T per 16-key tile; exp2 + pack; concat pairs -> x32 A-frags
    bf16x8 apack[4][2];
    #pragma unroll
    for (int t = 0; t < 2; ++t) {
      const bf16x8 kf00 = *(const bf16x8*)&Kl[kRi[4 * t + 0]];
      const bf16x8 kf01 = *(const bf16x8*)&Kl[kRi[4 * t + 1]];
      const bf16x8 kf10 = *(const bf16x8*)&Kl[kRi[4 * t + 2]];
      const bf16x8 kf11 = *(const bf16x8*)&Kl[kRi[4 * t + 3]];
      #pragma unroll
      for (int s = 0; s < 4; ++s) {
        f32x4 sa = {0.f,0.f,0.f,0.f}, sb = {0.f,0.f,0.f,0.f};
        sa = __builtin_amdgcn_mfma_f32_16x16x32_bf16(kf00, aq[s][0], sa, 0, 0, 0);
        sa = __builtin_amdgcn_mfma_f32_16x16x32_bf16(kf01, aq[s][1], sa, 0, 0, 0);
        sb = __builtin_amdgcn_mfma_f32_16x16x32_bf16(kf10, aq[s][0], sb, 0, 0, 0);
        sb = __builtin_amdgcn_mfma_f32_16x16x32_bf16(kf11, aq[s][1], sb, 0, 0, 0);
        union { unsigned u[4]; bf16x8 v; } pk;
        pk.u[0] = pktr(__builtin_amdgcn_exp2f(sa[0]), __builtin_amdgcn_exp2f(sa[1]));
        pk.u[1] = pktr(__builtin_amdgcn_exp2f(sa[2]), __builtin_amdgcn_exp2f(sa[3]));
        pk.u[2] = pktr(__builtin_amdgcn_exp2f(sb[0]), __builtin_amdgcn_exp2f(sb[1]));
        pk.u[3] = pktr(__builtin_amdgcn_exp2f(sb[2]), __builtin_amdgcn_exp2f(sb[3]));
        apack[s][t] = pk.v;
      }
    }

    __builtin_amdgcn_s_setprio(1);   // favor the pure-MFMA cluster (T5)
    #pragma unroll
    for (int dt = 0; dt < 4; ++dt) {
      const bf16x8 vb0 = *(const bf16x8*)&Vt[kRi[2 * dt]];
      const bf16x8 vb1 = *(const bf16x8*)&Vt[kRi[2 * dt + 1]];
      #pragma unroll
      for (int s = 0; s < 4; ++s) {
        o[s][dt] = __builtin_amdgcn_mfma_f32_16x16x32_bf16(apack[s][0], vb0, o[s][dt], 0, 0, 0);
        o[s][dt] = __builtin_amdgcn_mfma_f32_16x16x32_bf16(apack[s][1], vb1, o[s][dt], 0, 0, 0);
      }
    }
    #pragma unroll
    for (int s = 0; s < 4; ++s) {
      lacc[s] = __builtin_amdgcn_mfma_f32_16x16x32_bf16(apack[s][0], bones8, lacc[s], 0, 0, 0);
      lacc[s] = __builtin_amdgcn_mfma_f32_16x16x32_bf16(apack[s][1], bones8, lacc[s], 0, 0, 0);
    }
    __builtin_amdgcn_s_setprio(0);
  }

  // epilogue: plain stores of partials (each element written exactly once)
  float* __restrict__ Od = (sp == 0) ? O : Opb + (size_t)(sp - 1) * S_LEN * HID;
  #pragma unroll
  for (int s = 0; s < 4; ++s) {
    #pragma unroll
    for (int dt = 0; dt < 4; ++dt) {
      #pragma unroll
      for (int r = 0; r < 4; ++r) {
        const int row = q0 + wave * 64 + s * 16 + 4 * g + r;
        Od[(size_t)row * HID + h * HD + dt * 16 + c] = o[s][dt][r];
      }
    }
  }
  if (c == 0) {
    #pragma unroll
    for (int s = 0; s < 4; ++s)
      #pragma unroll
      for (int r = 0; r < 4; ++r) {
        const int row = q0 + wave * 64 + s * 16 + 4 * g + r;
        Lp[((size_t)sp * NH + h) * S_LEN + row] = lacc[s][r];
      }
  }
}

// ---------------------------------------------------------------------------
// Kernel 3: merge the NSP KV-split partials and normalize by the softmax
// denominator. Pure-BW.
// ---------------------------------------------------------------------------
template<int NSP>
__global__ __launch_bounds__(256) void reduce_norm(float* __restrict__ O,
                                                   const float* __restrict__ Opb,
                                                   const float* __restrict__ Lp)
{
  const int i = blockIdx.x * 256 + threadIdx.x;
  float4 a = ((const float4*)O)[i];
  const int idx4 = i * 4;
  const int row = idx4 / HID;
  const int h   = (idx4 % HID) >> 6;
  float l = Lp[h * S_LEN + row];
  #pragma unroll
  for (int s = 1; s < NSP; ++s) {
    const float4 b = ((const float4*)(Opb + (size_t)(s - 1) * S_LEN * HID))[i];
    a.x += b.x; a.y += b.y; a.z += b.z; a.w += b.w;
    l += Lp[((size_t)s * NH + h) * S_LEN + row];
  }
  const float inv = 1.0f / l;
  a.x *= inv; a.y *= inv; a.z *= inv; a.w *= inv;
  ((float4*)O)[i] = a;
}

// ---------------------------------------------------------------------------
extern "C" void kernel_launch(void* const* d_in, const int* in_sizes, int n_in,
                              void* d_out, int out_size, void* d_ws, size_t ws_size,
                              hipStream_t stream) {
  const float* X  = (const float*)d_in[0];
  const float* Wq = (const float*)d_in[1];
  const float* bq = (const float*)d_in[2];
  const float* Wk = (const float*)d_in[3];
  const float* bk = (const float*)d_in[4];
  const float* Wv = (const float*)d_in[5];
  const float* bv = (const float*)d_in[6];

  unsigned short* Xb = (unsigned short*)d_ws;
  unsigned short* Wt = Xb + (size_t)S_LEN * HID;
  unsigned short* Qb = Wt + (size_t)3 * HID * HID;
  unsigned short* Kb = Qb + (size_t)NH * S_LEN * HD;
  unsigned short* Vb = Kb + (size_t)NH * S_LEN * HD;
  float* Opb = (float*)(Vb + (size_t)NH * S_LEN * HD);

  // bytes needed for NSP=4: bf16 bufs + 3 O-partials + 4*NH*S L-partials
  const size_t ush = (size_t)S_LEN * HID + (size_t)3 * HID * HID + (size_t)3 * NH * S_LEN * HD;
  const size_t need4 = ush * 2 + ((size_t)3 * S_LEN * HID + (size_t)4 * NH * S_LEN) * 4;
  const bool s4 = ws_size >= need4;

  float* Lp = Opb + (size_t)(s4 ? 3 : 1) * S_LEN * HID;
  float* O = (float*)d_out;

  prep<<<dim3(3504), 256, 0, stream>>>(X, Wq, Wk, Wv, Xb, Wt);
  qkv_proj<<<dim3(12, 32, 3), 256, 0, stream>>>(Xb, Wt, bq, bk, bv, Qb, Kb, Vb);
  if (s4) {
    attn<4><<<dim3(768), 256, 0, stream>>>(Qb, Kb, Vb, O, Opb, Lp);
    reduce_norm<4><<<dim3((S_LEN * HID / 4) / 256), 256, 0, stream>>>(O, Opb, Lp);
  } else {
    attn<2><<<dim3(384), 256, 0, stream>>>(Qb, Kb, Vb, O, Opb, Lp);
    reduce_norm<2><<<dim3((S_LEN * HID / 4) / 256), 256, 0, stream>>>(O, Opb, Lp);
  }
}